// Round 1
// 499.227 us; speedup vs baseline: 1.0422x; 1.0422x over previous
//
#include <hip/hip_runtime.h>

typedef __bf16 bf16;
typedef __bf16 bf16x8 __attribute__((ext_vector_type(8)));
typedef float f32x4 __attribute__((ext_vector_type(4)));

#define BS 4
#define S 2048
#define D 256
#define H 4
#define HD 1024
#define NROW 8192  // BS*S

__device__ __forceinline__ void load_lds16(const bf16* g, bf16* l) {
    __builtin_amdgcn_global_load_lds(
        (const __attribute__((address_space(1))) void*)g,
        (__attribute__((address_space(3))) void*)l, 16, 0, 0);
}

// ---------------- prep: convert x to bf16 (+ transposed per-batch copy) ----
__global__ void prep_x(const float* __restrict__ x, bf16* __restrict__ x_bf,
                       bf16* __restrict__ xT_bf) {
    int idx = blockIdx.x * 256 + threadIdx.x;  // 0 .. 2097151
    float v = x[idx];
    x_bf[idx] = (bf16)v;
    int dd = idx & (D - 1);
    int t = idx >> 8;        // b*S + j
    int j = t & (S - 1);
    int b = t >> 11;
    xT_bf[(size_t)b * D * S + (size_t)dd * S + j] = (bf16)v;
}

// ---------------- prep: transpose weights to (N,K) bf16; Wq scaled ---------
__global__ void prep_w(const float* __restrict__ Wq, const float* __restrict__ Wk,
                       const float* __restrict__ Wv, bf16* __restrict__ WqT,
                       bf16* __restrict__ WkT, bf16* __restrict__ WvT) {
    int idx = blockIdx.x * 256 + threadIdx.x;  // 0 .. 786431
    const float SCALE = 0.09016844005556021f;  // log2(e)/16 : exp2-domain logits
    int seg = idx >> 18;
    int r = idx & 262143;
    if (seg == 0) {
        int k = r & 255, n = r >> 8;           // WqT[n][k] = Wq[k][n]*SCALE
        WqT[r] = (bf16)(Wq[k * HD + n] * SCALE);
    } else if (seg == 1) {
        int k = r & 255, n = r >> 8;
        WkT[r] = (bf16)(Wk[k * HD + n]);
    } else {
        int k = r & 1023, n = r >> 10;         // WvT[n][k] = Wv[k][n]
        WvT[r] = (bf16)(Wv[k * D + n]);
    }
}

// ---------------- NT GEMM: C(MxN) = A(MxK) * B(NxK)^T, bf16 out ------------
__global__ __launch_bounds__(256) void gemm_nt_bf16(
    const bf16* __restrict__ A, const bf16* __restrict__ B0,
    const bf16* __restrict__ B1, bf16* __restrict__ C0, bf16* __restrict__ C1,
    int N, int Kd) {
    const bf16* B = blockIdx.z ? B1 : B0;
    bf16* C = blockIdx.z ? C1 : C0;
    int n0 = blockIdx.x * 64;
    int m0 = blockIdx.y * 64;
    __shared__ __align__(16) bf16 As[64 * 40];
    __shared__ __align__(16) bf16 Bs[64 * 40];
    int t = threadIdx.x, w = t >> 6, l = t & 63;
    int lr = l & 15, lq = l >> 4;
    f32x4 acc[4] = {};
    for (int k0 = 0; k0 < Kd; k0 += 32) {
        int row = t >> 2, cb = (t & 3) * 8;
        bf16x8 va = *(const bf16x8*)&A[(size_t)(m0 + row) * Kd + k0 + cb];
        *(bf16x8*)&As[row * 40 + cb] = va;
        bf16x8 vb = *(const bf16x8*)&B[(size_t)(n0 + row) * Kd + k0 + cb];
        *(bf16x8*)&Bs[row * 40 + cb] = vb;
        __syncthreads();
        bf16x8 af = *(const bf16x8*)&As[(w * 16 + lr) * 40 + lq * 8];
#pragma unroll
        for (int nt = 0; nt < 4; nt++) {
            bf16x8 bfr = *(const bf16x8*)&Bs[(nt * 16 + lr) * 40 + lq * 8];
            acc[nt] = __builtin_amdgcn_mfma_f32_16x16x32_bf16(af, bfr, acc[nt], 0, 0, 0);
        }
        __syncthreads();
    }
#pragma unroll
    for (int nt = 0; nt < 4; nt++)
#pragma unroll
        for (int rr = 0; rr < 4; rr++) {
            int row = m0 + w * 16 + lq * 4 + rr;
            C[(size_t)row * N + n0 + nt * 16 + lr] = (bf16)acc[nt][rr];
        }
}

// ---- staging helpers for attn: K tile 32x256, xT tile 256x32 --------------
// K swizzle s(r) = (r&3)|((r&1)<<2): per-16-lane-quarter the XOR hits
// {0,5,2,7} -> bit2 varies -> 2 lanes per 16B granule (conflict-free b128).
__device__ __forceinline__ void stage_k_tile(const bf16* __restrict__ K,
                                             bf16* kb, int j0, int w, int l) {
    int krow = (w << 3) + (l >> 5);
    int kc = l & 31;
#pragma unroll
    for (int n = 0; n < 4; n++) {
        int r = krow + (n << 1);
        int cg = kc ^ ((r & 3) | ((r & 1) << 2));
        load_lds16(&K[(size_t)(j0 + r) * D + cg * 8], &kb[((w << 3) + (n << 1)) * 256]);
    }
}

__device__ __forceinline__ void stage_x_tile(const bf16* __restrict__ xTb,
                                             bf16* xb, int j0, int w, int l) {
    int xrow = (w << 6) + (l >> 2);
    int xc = l & 3;
#pragma unroll
    for (int n = 0; n < 4; n++) {
        int dd = xrow + (n << 4);
        int cg = xc ^ (dd & 3);
        load_lds16(&xTb[(size_t)dd * S + j0 + cg * 8], &xb[((w << 6) + (n << 4)) * 32]);
    }
}

// ---- fused attention: double-buffered pipelined staging, XCD-local bh -----
// 512 blocks 1D; bijective remap lb=(n&7)*64+(n>>3) puts the 64 blocks of
// 2 consecutive bh on one XCD -> K(2MB)+xT(1MB) stay L2-resident.
// Per j-tile: issue next-tile global_load_lds, s_waitcnt vmcnt(N) (counted,
// never a full drain in steady state), raw s_barrier, compute, s_barrier.
__global__ __launch_bounds__(256, 2) void attn_fused(
    const bf16* __restrict__ Qbf, const bf16* __restrict__ Kbf,
    const bf16* __restrict__ xT, float* __restrict__ probs,
    bf16* __restrict__ attn) {
    int nblk = blockIdx.x;
    int lb = (nblk & 7) * 64 + (nblk >> 3);  // XCD-contiguous linear block id
    int bh = lb >> 5, b = bh >> 2, h = bh & 3;
    int t = threadIdx.x, w = t >> 6, l = t & 63;
    int lr = l & 15, lq = l >> 4;
    int sw = (lr & 3) | ((lr & 1) << 2);     // K read-side swizzle (matches stager)
    const bf16* Q = Qbf + (size_t)bh * S * D;
    const bf16* K = Kbf + (size_t)bh * S * D;
    const bf16* xTb = xT + (size_t)b * D * S;
    int ibase = (lb & 31) * 64 + w * 16;

    __shared__ __align__(16) bf16 kbuf[2][32 * 256];  // 2 x 16 KB
    __shared__ __align__(16) bf16 xbuf[2][256 * 32];  // 2 x 16 KB
    __shared__ __align__(16) bf16 pl[4][16 * 40];     // 5 KB

    bf16x8 qf[8];
#pragma unroll
    for (int kf = 0; kf < 8; kf++)
        qf[kf] = *(const bf16x8*)&Q[(size_t)(ibase + lr) * D + kf * 32 + lq * 8];

    // ---- sweep 1: l = sum_j exp2(s_ij) (no max; s ~ O(10), fp32-safe) ----
    float lsum[4] = {0.f, 0.f, 0.f, 0.f};
    stage_k_tile(K, kbuf[0], 0, w, l);
    for (int it = 0; it < 64; it++) {
        int cur = it & 1;
        if (it < 63) {
            stage_k_tile(K, kbuf[cur ^ 1], (it + 1) << 5, w, l);
            asm volatile("s_waitcnt vmcnt(4)" ::: "memory");
        } else {
            asm volatile("s_waitcnt vmcnt(0)" ::: "memory");
        }
        __builtin_amdgcn_s_barrier();
#pragma unroll
        for (int subj = 0; subj < 2; subj++) {
            f32x4 acc = {};
#pragma unroll
            for (int kf = 0; kf < 8; kf++) {
                bf16x8 kfr = *(const bf16x8*)
                    &kbuf[cur][(subj * 16 + lr) * 256 + (((kf * 4 + lq) ^ sw) * 8)];
                acc = __builtin_amdgcn_mfma_f32_16x16x32_bf16(qf[kf], kfr, acc, 0, 0, 0);
            }
#pragma unroll
            for (int r = 0; r < 4; r++) lsum[r] += exp2f(acc[r]);
        }
        __builtin_amdgcn_s_barrier();  // readers done -> next stage may overwrite
    }
    float li[4];
#pragma unroll
    for (int r = 0; r < 4; r++) {
        float s = lsum[r];
        for (int off = 1; off < 16; off <<= 1) s += __shfl_xor(s, off);
        li[r] = 1.0f / s;
    }

    // ---- sweep 2: recompute scores, write probs f32, fused PV ----
    f32x4 oacc[16] = {};
    float* probb = probs + (size_t)bh * S * S;
    stage_k_tile(K, kbuf[0], 0, w, l);
    stage_x_tile(xTb, xbuf[0], 0, w, l);
    for (int it = 0; it < 64; it++) {
        int cur = it & 1;
        int j0 = it << 5;
        if (it < 63) {
            stage_k_tile(K, kbuf[cur ^ 1], j0 + 32, w, l);
            stage_x_tile(xTb, xbuf[cur ^ 1], j0 + 32, w, l);
            // 8 new loads newest; waiting vmcnt(8) also drains prev-iter's
            // 2 probs stores (older) -> current tile guaranteed resident.
            asm volatile("s_waitcnt vmcnt(8)" ::: "memory");
        } else {
            asm volatile("s_waitcnt vmcnt(0)" ::: "memory");
        }
        __builtin_amdgcn_s_barrier();
#pragma unroll
        for (int subj = 0; subj < 2; subj++) {
            f32x4 acc = {};
#pragma unroll
            for (int kf = 0; kf < 8; kf++) {
                bf16x8 kfr = *(const bf16x8*)
                    &kbuf[cur][(subj * 16 + lr) * 256 + (((kf * 4 + lq) ^ sw) * 8)];
                acc = __builtin_amdgcn_mfma_f32_16x16x32_bf16(qf[kf], kfr, acc, 0, 0, 0);
            }
#pragma unroll
            for (int r = 0; r < 4; r++) {
                float p = exp2f(acc[r]) * li[r];
                pl[w][(lq * 4 + r) * 40 + subj * 16 + lr] = (bf16)p;
            }
        }
        // same-wave C->A layout round-trip (lgkmcnt only, no barrier)
        bf16x8 pf = *(const bf16x8*)&pl[w][lr * 40 + lq * 8];
        f32x4 p0, p1;
#pragma unroll
        for (int e = 0; e < 4; e++) { p0[e] = (float)pf[e]; p1[e] = (float)pf[e + 4]; }
        float* pp = &probb[(size_t)(ibase + lr) * S + j0 + lq * 8];
        *(f32x4*)pp = p0;
        *(f32x4*)(pp + 4) = p1;
#pragma unroll
        for (int dt = 0; dt < 16; dt++) {
            int dd = dt * 16 + lr;
            bf16x8 xf = *(const bf16x8*)&xbuf[cur][dd * 32 + ((lq ^ (lr & 3)) * 8)];
            oacc[dt] = __builtin_amdgcn_mfma_f32_16x16x32_bf16(pf, xf, oacc[dt], 0, 0, 0);
        }
        __builtin_amdgcn_s_barrier();  // readers done -> next stage may overwrite
    }
#pragma unroll
    for (int dt = 0; dt < 16; dt++)
#pragma unroll
        for (int rr = 0; rr < 4; rr++) {
            int row = ibase + lq * 4 + rr;
            attn[((size_t)(b * S + row)) * HD + h * D + dt * 16 + lr] = (bf16)oacc[dt][rr];
        }
}

// ------- final: out = attn @ Wv + x, then LayerNorm ------------------------
// block = 256 threads = 4 waves; 16 rows/block; wave w owns cols w*64..w*64+63
__global__ __launch_bounds__(256) void out_gemm_ln(
    const bf16* __restrict__ attn, const bf16* __restrict__ WvT,
    const float* __restrict__ x, const float* __restrict__ gamma,
    const float* __restrict__ beta, float* __restrict__ out) {
    int m0 = blockIdx.x * 16;
    int t = threadIdx.x, w = t >> 6, l = t & 63;
    int lr = l & 15, lq = l >> 4;
    int ncol0 = w * 64;
    f32x4 acc[4] = {};
    for (int k0 = 0; k0 < HD; k0 += 32) {
        bf16x8 af = *(const bf16x8*)&attn[(size_t)(m0 + lr) * HD + k0 + lq * 8];
#pragma unroll
        for (int dt = 0; dt < 4; dt++) {
            bf16x8 bfr =
                *(const bf16x8*)&WvT[(size_t)(ncol0 + dt * 16 + lr) * HD + k0 + lq * 8];
            acc[dt] = __builtin_amdgcn_mfma_f32_16x16x32_bf16(af, bfr, acc[dt], 0, 0, 0);
        }
    }
    float sum[4] = {0, 0, 0, 0}, sq[4] = {0, 0, 0, 0};
#pragma unroll
    for (int dt = 0; dt < 4; dt++)
#pragma unroll
        for (int rr = 0; rr < 4; rr++) {
            int row = m0 + lq * 4 + rr;
            float v = acc[dt][rr] + x[(size_t)row * D + ncol0 + dt * 16 + lr];
            acc[dt][rr] = v;
            sum[rr] += v;
            sq[rr] += v * v;
        }
#pragma unroll
    for (int rr = 0; rr < 4; rr++)
        for (int off = 1; off < 16; off <<= 1) {
            sum[rr] += __shfl_xor(sum[rr], off);
            sq[rr] += __shfl_xor(sq[rr], off);
        }
    __shared__ float part[4][16][2];
    if (lr == 0)
#pragma unroll
        for (int rr = 0; rr < 4; rr++) {
            part[w][lq * 4 + rr][0] = sum[rr];
            part[w][lq * 4 + rr][1] = sq[rr];
        }
    __syncthreads();
    float mu[4], rs[4];
#pragma unroll
    for (int rr = 0; rr < 4; rr++) {
        int rowi = lq * 4 + rr;
        float s = part[0][rowi][0] + part[1][rowi][0] + part[2][rowi][0] + part[3][rowi][0];
        float q = part[0][rowi][1] + part[1][rowi][1] + part[2][rowi][1] + part[3][rowi][1];
        mu[rr] = s * (1.0f / 256.0f);
        float var = q * (1.0f / 256.0f) - mu[rr] * mu[rr];
        rs[rr] = rsqrtf(var + 1e-5f);
    }
#pragma unroll
    for (int dt = 0; dt < 4; dt++) {
        int col = ncol0 + dt * 16 + lr;
        float g = gamma[col], be = beta[col];
#pragma unroll
        for (int rr = 0; rr < 4; rr++) {
            float v = (acc[dt][rr] - mu[rr]) * rs[rr] * g + be;
            out[(size_t)(m0 + lq * 4 + rr) * D + col] = v;
        }
    }
}

extern "C" void kernel_launch(void* const* d_in, const int* in_sizes, int n_in,
                              void* d_out, int out_size, void* d_ws, size_t ws_size,
                              hipStream_t stream) {
    const float* x = (const float*)d_in[0];
    const float* Wq = (const float*)d_in[1];
    const float* Wk = (const float*)d_in[2];
    const float* Wv = (const float*)d_in[3];
    const float* gamma = (const float*)d_in[4];
    const float* beta = (const float*)d_in[5];
    float* out = (float*)d_out;
    float* probs = out + (size_t)NROW * D;  // 2,097,152 floats of `out` first

    char* ws = (char*)d_ws;
    bf16* x_bf = (bf16*)ws;                      // 4 MB
    bf16* xT_bf = (bf16*)(ws + 4194304);         // 4 MB
    bf16* WqT = (bf16*)(ws + 8388608);           // 512 KB
    bf16* WkT = (bf16*)(ws + 8912896);           // 512 KB
    bf16* WvT = (bf16*)(ws + 9437184);           // 512 KB
    bf16* Qbf = (bf16*)(ws + 9961472);           // 16 MB
    bf16* Kbf = (bf16*)(ws + 26738688);          // 16 MB
    bf16* attn = (bf16*)(ws + 43515904);         // 16 MB

    prep_x<<<8192, 256, 0, stream>>>(x, x_bf, xT_bf);
    prep_w<<<3072, 256, 0, stream>>>(Wq, Wk, Wv, WqT, WkT, WvT);
    gemm_nt_bf16<<<dim3(16, 128, 2), 256, 0, stream>>>(x_bf, WqT, WkT, Qbf, Kbf,
                                                       HD, D);
    attn_fused<<<dim3(512), 256, 0, stream>>>(Qbf, Kbf, xT_bf, probs, attn);
    out_gemm_ln<<<512, 256, 0, stream>>>(attn, WvT, x, gamma, beta, out);
}

// Round 2
// 490.448 us; speedup vs baseline: 1.0609x; 1.0179x over previous
//
#include <hip/hip_runtime.h>

typedef __bf16 bf16;
typedef __bf16 bf16x4 __attribute__((ext_vector_type(4)));
typedef __bf16 bf16x8 __attribute__((ext_vector_type(8)));
typedef float f32x4 __attribute__((ext_vector_type(4)));

#define BS 4
#define S 2048
#define D 256
#define H 4
#define HD 1024
#define NROW 8192  // BS*S

__device__ __forceinline__ void load_lds16(const bf16* g, bf16* l) {
    __builtin_amdgcn_global_load_lds(
        (const __attribute__((address_space(1))) void*)g,
        (__attribute__((address_space(3))) void*)l, 16, 0, 0);
}

// ---------------- prep: x -> bf16 copy + LDS-tiled transpose ---------------
// grid (32,4,4) = (j-tile, d-tile, b); 256 thr; 64x64 f32 tile per block.
__global__ __launch_bounds__(256) void prep_x(const float* __restrict__ x,
                                              bf16* __restrict__ x_bf,
                                              bf16* __restrict__ xT_bf) {
    __shared__ bf16 tile[64][68];
    int j0 = blockIdx.x * 64, d0 = blockIdx.y * 64, b = blockIdx.z;
    int t = threadIdx.x;
    int rsub = t >> 4;        // 0..15
    int c4 = (t & 15) * 4;    // 0..60
#pragma unroll
    for (int rr = 0; rr < 4; rr++) {
        int j = rr * 16 + rsub;
        float4 v = *(const float4*)&x[((size_t)(b * S + j0 + j)) * D + d0 + c4];
        bf16 b0 = (bf16)v.x, b1 = (bf16)v.y, b2 = (bf16)v.z, b3 = (bf16)v.w;
        tile[j][c4 + 0] = b0;
        tile[j][c4 + 1] = b1;
        tile[j][c4 + 2] = b2;
        tile[j][c4 + 3] = b3;
        bf16x4 o = {b0, b1, b2, b3};
        *(bf16x4*)&x_bf[((size_t)(b * S + j0 + j)) * D + d0 + c4] = o;
    }
    __syncthreads();
#pragma unroll
    for (int rr = 0; rr < 4; rr++) {
        int dd = rr * 16 + rsub;
        bf16x4 o;
        o[0] = tile[c4 + 0][dd];
        o[1] = tile[c4 + 1][dd];
        o[2] = tile[c4 + 2][dd];
        o[3] = tile[c4 + 3][dd];
        *(bf16x4*)&xT_bf[(size_t)b * D * S + (size_t)(d0 + dd) * S + j0 + c4] = o;
    }
}

// ---------------- prep: weights -> (N,K) bf16 via LDS tile transpose -------
__device__ __forceinline__ void tile_tr64(const float* __restrict__ src,
                                          bf16* __restrict__ dst, int ldsrc,
                                          int lddst, int r0, int c0, float scale,
                                          bf16 (&tile)[64][68], int t) {
    int rsub = t >> 4, c4 = (t & 15) * 4;
#pragma unroll
    for (int rr = 0; rr < 4; rr++) {
        int r = rr * 16 + rsub;
        float4 v = *(const float4*)&src[(size_t)(r0 + r) * ldsrc + c0 + c4];
        tile[r][c4 + 0] = (bf16)(v.x * scale);
        tile[r][c4 + 1] = (bf16)(v.y * scale);
        tile[r][c4 + 2] = (bf16)(v.z * scale);
        tile[r][c4 + 3] = (bf16)(v.w * scale);
    }
    __syncthreads();
#pragma unroll
    for (int rr = 0; rr < 4; rr++) {
        int c = rr * 16 + rsub;
        bf16x4 o;
        o[0] = tile[c4 + 0][c];
        o[1] = tile[c4 + 1][c];
        o[2] = tile[c4 + 2][c];
        o[3] = tile[c4 + 3][c];
        *(bf16x4*)&dst[(size_t)(c0 + c) * lddst + r0 + c4] = o;
    }
}

// grid 192: [0,64) Wq (256x1024), [64,128) Wk (256x1024), [128,192) Wv (1024x256)
__global__ __launch_bounds__(256) void prep_w(const float* __restrict__ Wq,
                                              const float* __restrict__ Wk,
                                              const float* __restrict__ Wv,
                                              bf16* __restrict__ WqT,
                                              bf16* __restrict__ WkT,
                                              bf16* __restrict__ WvT) {
    __shared__ bf16 tile[64][68];
    const float SCALE = 0.09016844005556021f;  // log2(e)/16 : exp2-domain logits
    int bx = blockIdx.x, t = threadIdx.x;
    if (bx < 64) {
        int rt = bx & 3, ct = bx >> 2;
        tile_tr64(Wq, WqT, HD, D, rt * 64, ct * 64, SCALE, tile, t);
    } else if (bx < 128) {
        int b2 = bx - 64;
        int rt = b2 & 3, ct = b2 >> 2;
        tile_tr64(Wk, WkT, HD, D, rt * 64, ct * 64, 1.0f, tile, t);
    } else {
        int b2 = bx - 128;
        int rt = b2 & 15, ct = b2 >> 4;
        tile_tr64(Wv, WvT, D, HD, rt * 64, ct * 64, 1.0f, tile, t);
    }
}

// ---------------- NT GEMM: C(MxN) = A(MxK) * B(NxK)^T, K=256 single-stage --
// Full K fits LDS: 32KB A-tile + 32KB B-tile, one barrier, 32 MFMA.
__global__ __launch_bounds__(256) void gemm_nt_bf16(
    const bf16* __restrict__ A, const bf16* __restrict__ B0,
    const bf16* __restrict__ B1, bf16* __restrict__ C0, bf16* __restrict__ C1,
    int N, int Kd) {
    const bf16* B = blockIdx.z ? B1 : B0;
    bf16* C = blockIdx.z ? C1 : C0;
    int n0 = blockIdx.x * 64;
    int m0 = blockIdx.y * 64;
    __shared__ __align__(16) bf16 As[64 * 256];
    __shared__ __align__(16) bf16 Bs[64 * 256];
    int t = threadIdx.x, w = t >> 6, l = t & 63;
    int lr = l & 15, lq = l >> 4;
    // stage: wave w owns rows [w*16, w*16+16); each load = 2 rows (1KB)
#pragma unroll
    for (int n = 0; n < 8; n++) {
        int r = w * 16 + 2 * n + (l >> 5);
        int cg = (l & 31) ^ (r & 7);
        load_lds16(&A[(size_t)(m0 + r) * D + cg * 8], &As[(w * 16 + 2 * n) * 256]);
        load_lds16(&B[(size_t)(n0 + r) * D + cg * 8], &Bs[(w * 16 + 2 * n) * 256]);
    }
    asm volatile("s_waitcnt vmcnt(0)" ::: "memory");
    __builtin_amdgcn_s_barrier();
    f32x4 acc[4] = {};
#pragma unroll
    for (int kf = 0; kf < 8; kf++) {
        bf16x8 af = *(const bf16x8*)&As[(w * 16 + lr) * 256 + (((kf * 4 + lq) ^ (lr & 7)) * 8)];
#pragma unroll
        for (int nt = 0; nt < 4; nt++) {
            bf16x8 bfr =
                *(const bf16x8*)&Bs[(nt * 16 + lr) * 256 + (((kf * 4 + lq) ^ (lr & 7)) * 8)];
            acc[nt] = __builtin_amdgcn_mfma_f32_16x16x32_bf16(af, bfr, acc[nt], 0, 0, 0);
        }
    }
#pragma unroll
    for (int nt = 0; nt < 4; nt++)
#pragma unroll
        for (int rr = 0; rr < 4; rr++) {
            int row = m0 + w * 16 + lq * 4 + rr;
            C[(size_t)row * N + n0 + nt * 16 + lr] = (bf16)acc[nt][rr];
        }
}

// ---- staging helpers for attn: K tile 32x256, xT tile 256x32 --------------
// K swizzle ^(r&7): per-16-lane-quarter lr&7 hits 8 distinct 16B slots ->
// natural 2-way (conflict-free). xT swizzle ^((dd>>1)&3): rows alternate
// bank halves by parity; within a parity class (dd>>1)&3 spreads 8 lanes
// over 4 slots -> natural 2-way.
__device__ __forceinline__ void stage_k_tile(const bf16* __restrict__ K,
                                             bf16* kb, int j0, int w, int l) {
    int krow = (w << 3) + (l >> 5);
    int kc = l & 31;
#pragma unroll
    for (int n = 0; n < 4; n++) {
        int r = krow + (n << 1);
        int cg = kc ^ (r & 7);
        load_lds16(&K[(size_t)(j0 + r) * D + cg * 8], &kb[((w << 3) + (n << 1)) * 256]);
    }
}

__device__ __forceinline__ void stage_x_tile(const bf16* __restrict__ xTb,
                                             bf16* xb, int j0, int w, int l) {
    int xrow = (w << 6) + (l >> 2);
    int xc = l & 3;
#pragma unroll
    for (int n = 0; n < 4; n++) {
        int dd = xrow + (n << 4);
        int cg = xc ^ ((dd >> 1) & 3);
        load_lds16(&xTb[(size_t)dd * S + j0 + cg * 8], &xb[((w << 6) + (n << 4)) * 32]);
    }
}

// ---- fused attention: double-buffered pipelined staging, XCD-local bh -----
__global__ __launch_bounds__(256, 2) void attn_fused(
    const bf16* __restrict__ Qbf, const bf16* __restrict__ Kbf,
    const bf16* __restrict__ xT, float* __restrict__ probs,
    bf16* __restrict__ attn) {
    int nblk = blockIdx.x;
    int lb = (nblk & 7) * 64 + (nblk >> 3);  // XCD-contiguous linear block id
    int bh = lb >> 5, b = bh >> 2, h = bh & 3;
    int t = threadIdx.x, w = t >> 6, l = t & 63;
    int lr = l & 15, lq = l >> 4;
    const bf16* Q = Qbf + (size_t)bh * S * D;
    const bf16* K = Kbf + (size_t)bh * S * D;
    const bf16* xTb = xT + (size_t)b * D * S;
    int ibase = (lb & 31) * 64 + w * 16;

    __shared__ __align__(16) bf16 kbuf[2][32 * 256];  // 2 x 16 KB
    __shared__ __align__(16) bf16 xbuf[2][256 * 32];  // 2 x 16 KB
    __shared__ __align__(16) bf16 pl[4][16 * 40];     // 5 KB

    bf16x8 qf[8];
#pragma unroll
    for (int kf = 0; kf < 8; kf++)
        qf[kf] = *(const bf16x8*)&Q[(size_t)(ibase + lr) * D + kf * 32 + lq * 8];

    // ---- sweep 1: l = sum_j exp2(s_ij) (no max; s ~ O(10), fp32-safe) ----
    float lsum[4] = {0.f, 0.f, 0.f, 0.f};
    stage_k_tile(K, kbuf[0], 0, w, l);
    for (int it = 0; it < 64; it++) {
        int cur = it & 1;
        if (it < 63) {
            stage_k_tile(K, kbuf[cur ^ 1], (it + 1) << 5, w, l);
            asm volatile("s_waitcnt vmcnt(4)" ::: "memory");
        } else {
            asm volatile("s_waitcnt vmcnt(0)" ::: "memory");
        }
        __builtin_amdgcn_s_barrier();
#pragma unroll
        for (int subj = 0; subj < 2; subj++) {
            f32x4 acc = {};
#pragma unroll
            for (int kf = 0; kf < 8; kf++) {
                bf16x8 kfr = *(const bf16x8*)
                    &kbuf[cur][(subj * 16 + lr) * 256 + (((kf * 4 + lq) ^ (lr & 7)) * 8)];
                acc = __builtin_amdgcn_mfma_f32_16x16x32_bf16(qf[kf], kfr, acc, 0, 0, 0);
            }
#pragma unroll
            for (int r = 0; r < 4; r++) lsum[r] += exp2f(acc[r]);
        }
        __builtin_amdgcn_s_barrier();  // readers done -> next stage may overwrite
    }
    float li[4];
#pragma unroll
    for (int r = 0; r < 4; r++) {
        float s = lsum[r];
        for (int off = 1; off < 16; off <<= 1) s += __shfl_xor(s, off);
        li[r] = 1.0f / s;
    }

    // ---- sweep 2: recompute scores, write probs f32, fused PV ----
    f32x4 oacc[16] = {};
    float* probb = probs + (size_t)bh * S * S;
    stage_k_tile(K, kbuf[0], 0, w, l);
    stage_x_tile(xTb, xbuf[0], 0, w, l);
    for (int it = 0; it < 64; it++) {
        int cur = it & 1;
        int j0 = it << 5;
        if (it < 63) {
            stage_k_tile(K, kbuf[cur ^ 1], j0 + 32, w, l);
            stage_x_tile(xTb, xbuf[cur ^ 1], j0 + 32, w, l);
            // 8 new loads newest; waiting vmcnt(8) also drains prev-iter's
            // 2 probs stores (older) -> current tile guaranteed resident.
            asm volatile("s_waitcnt vmcnt(8)" ::: "memory");
        } else {
            asm volatile("s_waitcnt vmcnt(0)" ::: "memory");
        }
        __builtin_amdgcn_s_barrier();
#pragma unroll
        for (int subj = 0; subj < 2; subj++) {
            f32x4 acc = {};
#pragma unroll
            for (int kf = 0; kf < 8; kf++) {
                bf16x8 kfr = *(const bf16x8*)
                    &kbuf[cur][(subj * 16 + lr) * 256 + (((kf * 4 + lq) ^ (lr & 7)) * 8)];
                acc = __builtin_amdgcn_mfma_f32_16x16x32_bf16(qf[kf], kfr, acc, 0, 0, 0);
            }
#pragma unroll
            for (int r = 0; r < 4; r++) {
                float p = exp2f(acc[r]) * li[r];
                pl[w][(lq * 4 + r) * 40 + subj * 16 + lr] = (bf16)p;
            }
        }
        // same-wave C->A layout round-trip (lgkmcnt only, no barrier)
        bf16x8 pf = *(const bf16x8*)&pl[w][lr * 40 + lq * 8];
        f32x4 p0, p1;
#pragma unroll
        for (int e = 0; e < 4; e++) { p0[e] = (float)pf[e]; p1[e] = (float)pf[e + 4]; }
        float* pp = &probb[(size_t)(ibase + lr) * S + j0 + lq * 8];
        *(f32x4*)pp = p0;
        *(f32x4*)(pp + 4) = p1;
#pragma unroll
        for (int dt = 0; dt < 16; dt++) {
            int dd = dt * 16 + lr;
            bf16x8 xf =
                *(const bf16x8*)&xbuf[cur][dd * 32 + ((lq ^ ((lr >> 1) & 3)) * 8)];
            oacc[dt] = __builtin_amdgcn_mfma_f32_16x16x32_bf16(pf, xf, oacc[dt], 0, 0, 0);
        }
        __builtin_amdgcn_s_barrier();  // readers done -> next stage may overwrite
    }
#pragma unroll
    for (int dt = 0; dt < 16; dt++)
#pragma unroll
        for (int rr = 0; rr < 4; rr++) {
            int row = ibase + lq * 4 + rr;
            attn[((size_t)(b * S + row)) * HD + h * D + dt * 16 + lr] = (bf16)oacc[dt][rr];
        }
}

// ------- final: out = attn @ Wv + x, then LayerNorm ------------------------
// block = 256 threads = 4 waves; 16 rows/block; wave w owns cols w*64..w*64+63
__global__ __launch_bounds__(256) void out_gemm_ln(
    const bf16* __restrict__ attn, const bf16* __restrict__ WvT,
    const float* __restrict__ x, const float* __restrict__ gamma,
    const float* __restrict__ beta, float* __restrict__ out) {
    int m0 = blockIdx.x * 16;
    int t = threadIdx.x, w = t >> 6, l = t & 63;
    int lr = l & 15, lq = l >> 4;
    int ncol0 = w * 64;
    f32x4 acc[4] = {};
    for (int k0 = 0; k0 < HD; k0 += 32) {
        bf16x8 af = *(const bf16x8*)&attn[(size_t)(m0 + lr) * HD + k0 + lq * 8];
#pragma unroll
        for (int dt = 0; dt < 4; dt++) {
            bf16x8 bfr =
                *(const bf16x8*)&WvT[(size_t)(ncol0 + dt * 16 + lr) * HD + k0 + lq * 8];
            acc[dt] = __builtin_amdgcn_mfma_f32_16x16x32_bf16(af, bfr, acc[dt], 0, 0, 0);
        }
    }
    float sum[4] = {0, 0, 0, 0}, sq[4] = {0, 0, 0, 0};
#pragma unroll
    for (int dt = 0; dt < 4; dt++)
#pragma unroll
        for (int rr = 0; rr < 4; rr++) {
            int row = m0 + lq * 4 + rr;
            float v = acc[dt][rr] + x[(size_t)row * D + ncol0 + dt * 16 + lr];
            acc[dt][rr] = v;
            sum[rr] += v;
            sq[rr] += v * v;
        }
#pragma unroll
    for (int rr = 0; rr < 4; rr++)
        for (int off = 1; off < 16; off <<= 1) {
            sum[rr] += __shfl_xor(sum[rr], off);
            sq[rr] += __shfl_xor(sq[rr], off);
        }
    __shared__ float part[4][16][2];
    if (lr == 0)
#pragma unroll
        for (int rr = 0; rr < 4; rr++) {
            part[w][lq * 4 + rr][0] = sum[rr];
            part[w][lq * 4 + rr][1] = sq[rr];
        }
    __syncthreads();
    float mu[4], rs[4];
#pragma unroll
    for (int rr = 0; rr < 4; rr++) {
        int rowi = lq * 4 + rr;
        float s = part[0][rowi][0] + part[1][rowi][0] + part[2][rowi][0] + part[3][rowi][0];
        float q = part[0][rowi][1] + part[1][rowi][1] + part[2][rowi][1] + part[3][rowi][1];
        mu[rr] = s * (1.0f / 256.0f);
        float var = q * (1.0f / 256.0f) - mu[rr] * mu[rr];
        rs[rr] = rsqrtf(var + 1e-5f);
    }
#pragma unroll
    for (int dt = 0; dt < 4; dt++) {
        int col = ncol0 + dt * 16 + lr;
        float g = gamma[col], be = beta[col];
#pragma unroll
        for (int rr = 0; rr < 4; rr++) {
            float v = (acc[dt][rr] - mu[rr]) * rs[rr] * g + be;
            out[(size_t)(m0 + lq * 4 + rr) * D + col] = v;
        }
    }
}

extern "C" void kernel_launch(void* const* d_in, const int* in_sizes, int n_in,
                              void* d_out, int out_size, void* d_ws, size_t ws_size,
                              hipStream_t stream) {
    const float* x = (const float*)d_in[0];
    const float* Wq = (const float*)d_in[1];
    const float* Wk = (const float*)d_in[2];
    const float* Wv = (const float*)d_in[3];
    const float* gamma = (const float*)d_in[4];
    const float* beta = (const float*)d_in[5];
    float* out = (float*)d_out;
    float* probs = out + (size_t)NROW * D;  // 2,097,152 floats of `out` first

    char* ws = (char*)d_ws;
    bf16* x_bf = (bf16*)ws;                      // 4 MB
    bf16* xT_bf = (bf16*)(ws + 4194304);         // 4 MB
    bf16* WqT = (bf16*)(ws + 8388608);           // 512 KB
    bf16* WkT = (bf16*)(ws + 8912896);           // 512 KB
    bf16* WvT = (bf16*)(ws + 9437184);           // 512 KB
    bf16* Qbf = (bf16*)(ws + 9961472);           // 16 MB
    bf16* Kbf = (bf16*)(ws + 26738688);          // 16 MB
    bf16* attn = (bf16*)(ws + 43515904);         // 16 MB

    prep_x<<<dim3(32, 4, 4), 256, 0, stream>>>(x, x_bf, xT_bf);
    prep_w<<<192, 256, 0, stream>>>(Wq, Wk, Wv, WqT, WkT, WvT);
    gemm_nt_bf16<<<dim3(16, 128, 2), 256, 0, stream>>>(x_bf, WqT, WkT, Qbf, Kbf,
                                                       HD, D);
    attn_fused<<<dim3(512), 256, 0, stream>>>(Qbf, Kbf, xT_bf, probs, attn);
    out_gemm_ln<<<512, 256, 0, stream>>>(attn, WvT, x, gamma, beta, out);
}

// Round 3
// 470.707 us; speedup vs baseline: 1.1054x; 1.0419x over previous
//
#include <hip/hip_runtime.h>

typedef __bf16 bf16;
typedef __bf16 bf16x4 __attribute__((ext_vector_type(4)));
typedef __bf16 bf16x8 __attribute__((ext_vector_type(8)));
typedef float f32x4 __attribute__((ext_vector_type(4)));

#define BS 4
#define S 2048
#define D 256
#define H 4
#define HD 1024
#define NROW 8192  // BS*S

__device__ __forceinline__ void load_lds16(const bf16* g, bf16* l) {
    __builtin_amdgcn_global_load_lds(
        (const __attribute__((address_space(1))) void*)g,
        (__attribute__((address_space(3))) void*)l, 16, 0, 0);
}

// ---------------- prep: x -> bf16 copy + LDS-tiled transpose ---------------
// grid (32,4,4) = (j-tile, d-tile, b); 256 thr; 64x64 f32 tile per block.
__global__ __launch_bounds__(256) void prep_x(const float* __restrict__ x,
                                              bf16* __restrict__ x_bf,
                                              bf16* __restrict__ xT_bf) {
    __shared__ bf16 tile[64][68];
    int j0 = blockIdx.x * 64, d0 = blockIdx.y * 64, b = blockIdx.z;
    int t = threadIdx.x;
    int rsub = t >> 4;        // 0..15
    int c4 = (t & 15) * 4;    // 0..60
#pragma unroll
    for (int rr = 0; rr < 4; rr++) {
        int j = rr * 16 + rsub;
        float4 v = *(const float4*)&x[((size_t)(b * S + j0 + j)) * D + d0 + c4];
        bf16 b0 = (bf16)v.x, b1 = (bf16)v.y, b2 = (bf16)v.z, b3 = (bf16)v.w;
        tile[j][c4 + 0] = b0;
        tile[j][c4 + 1] = b1;
        tile[j][c4 + 2] = b2;
        tile[j][c4 + 3] = b3;
        bf16x4 o = {b0, b1, b2, b3};
        *(bf16x4*)&x_bf[((size_t)(b * S + j0 + j)) * D + d0 + c4] = o;
    }
    __syncthreads();
#pragma unroll
    for (int rr = 0; rr < 4; rr++) {
        int dd = rr * 16 + rsub;
        bf16x4 o;
        o[0] = tile[c4 + 0][dd];
        o[1] = tile[c4 + 1][dd];
        o[2] = tile[c4 + 2][dd];
        o[3] = tile[c4 + 3][dd];
        *(bf16x4*)&xT_bf[(size_t)b * D * S + (size_t)(d0 + dd) * S + j0 + c4] = o;
    }
}

// ---------------- prep: weights -> (N,K) bf16 via LDS tile transpose -------
__device__ __forceinline__ void tile_tr64(const float* __restrict__ src,
                                          bf16* __restrict__ dst, int ldsrc,
                                          int lddst, int r0, int c0, float scale,
                                          bf16 (&tile)[64][68], int t) {
    int rsub = t >> 4, c4 = (t & 15) * 4;
#pragma unroll
    for (int rr = 0; rr < 4; rr++) {
        int r = rr * 16 + rsub;
        float4 v = *(const float4*)&src[(size_t)(r0 + r) * ldsrc + c0 + c4];
        tile[r][c4 + 0] = (bf16)(v.x * scale);
        tile[r][c4 + 1] = (bf16)(v.y * scale);
        tile[r][c4 + 2] = (bf16)(v.z * scale);
        tile[r][c4 + 3] = (bf16)(v.w * scale);
    }
    __syncthreads();
#pragma unroll
    for (int rr = 0; rr < 4; rr++) {
        int c = rr * 16 + rsub;
        bf16x4 o;
        o[0] = tile[c4 + 0][c];
        o[1] = tile[c4 + 1][c];
        o[2] = tile[c4 + 2][c];
        o[3] = tile[c4 + 3][c];
        *(bf16x4*)&dst[(size_t)(c0 + c) * lddst + r0 + c4] = o;
    }
}

// grid 192: [0,64) Wq (256x1024), [64,128) Wk (256x1024), [128,192) Wv (1024x256)
__global__ __launch_bounds__(256) void prep_w(const float* __restrict__ Wq,
                                              const float* __restrict__ Wk,
                                              const float* __restrict__ Wv,
                                              bf16* __restrict__ WqT,
                                              bf16* __restrict__ WkT,
                                              bf16* __restrict__ WvT) {
    __shared__ bf16 tile[64][68];
    const float SCALE = 0.09016844005556021f;  // log2(e)/16 : exp2-domain logits
    int bx = blockIdx.x, t = threadIdx.x;
    if (bx < 64) {
        int rt = bx & 3, ct = bx >> 2;
        tile_tr64(Wq, WqT, HD, D, rt * 64, ct * 64, SCALE, tile, t);
    } else if (bx < 128) {
        int b2 = bx - 64;
        int rt = b2 & 3, ct = b2 >> 2;
        tile_tr64(Wk, WkT, HD, D, rt * 64, ct * 64, 1.0f, tile, t);
    } else {
        int b2 = bx - 128;
        int rt = b2 & 15, ct = b2 >> 4;
        tile_tr64(Wv, WvT, D, HD, rt * 64, ct * 64, 1.0f, tile, t);
    }
}

// ---------------- NT GEMM: C(MxN) = A(MxK) * B(NxK)^T, K=256 single-stage --
__global__ __launch_bounds__(256) void gemm_nt_bf16(
    const bf16* __restrict__ A, const bf16* __restrict__ B0,
    const bf16* __restrict__ B1, bf16* __restrict__ C0, bf16* __restrict__ C1,
    int N, int Kd) {
    const bf16* B = blockIdx.z ? B1 : B0;
    bf16* C = blockIdx.z ? C1 : C0;
    int n0 = blockIdx.x * 64;
    int m0 = blockIdx.y * 64;
    __shared__ __align__(16) bf16 As[64 * 256];
    __shared__ __align__(16) bf16 Bs[64 * 256];
    int t = threadIdx.x, w = t >> 6, l = t & 63;
    int lr = l & 15, lq = l >> 4;
#pragma unroll
    for (int n = 0; n < 8; n++) {
        int r = w * 16 + 2 * n + (l >> 5);
        int cg = (l & 31) ^ (r & 7);
        load_lds16(&A[(size_t)(m0 + r) * D + cg * 8], &As[(w * 16 + 2 * n) * 256]);
        load_lds16(&B[(size_t)(n0 + r) * D + cg * 8], &Bs[(w * 16 + 2 * n) * 256]);
    }
    asm volatile("s_waitcnt vmcnt(0)" ::: "memory");
    __builtin_amdgcn_s_barrier();
    f32x4 acc[4] = {};
#pragma unroll
    for (int kf = 0; kf < 8; kf++) {
        bf16x8 af = *(const bf16x8*)&As[(w * 16 + lr) * 256 + (((kf * 4 + lq) ^ (lr & 7)) * 8)];
#pragma unroll
        for (int nt = 0; nt < 4; nt++) {
            bf16x8 bfr =
                *(const bf16x8*)&Bs[(nt * 16 + lr) * 256 + (((kf * 4 + lq) ^ (lr & 7)) * 8)];
            acc[nt] = __builtin_amdgcn_mfma_f32_16x16x32_bf16(af, bfr, acc[nt], 0, 0, 0);
        }
    }
#pragma unroll
    for (int nt = 0; nt < 4; nt++)
#pragma unroll
        for (int rr = 0; rr < 4; rr++) {
            int row = m0 + w * 16 + lq * 4 + rr;
            C[(size_t)row * N + n0 + nt * 16 + lr] = (bf16)acc[nt][rr];
        }
}

// ---- staging helpers for attn: K tile 32x256, xT tile 256x32 (group-local)
__device__ __forceinline__ void stage_k_tile(const bf16* __restrict__ K,
                                             bf16* kb, int j0, int lw, int l) {
    int krow = (lw << 3) + (l >> 5);
    int kc = l & 31;
#pragma unroll
    for (int n = 0; n < 4; n++) {
        int r = krow + (n << 1);
        int cg = kc ^ (r & 7);
        load_lds16(&K[(size_t)(j0 + r) * D + cg * 8], &kb[((lw << 3) + (n << 1)) * 256]);
    }
}

__device__ __forceinline__ void stage_x_tile(const bf16* __restrict__ xTb,
                                             bf16* xb, int j0, int lw, int l) {
    int xrow = (lw << 6) + (l >> 2);
    int xc = l & 3;
#pragma unroll
    for (int n = 0; n < 4; n++) {
        int dd = xrow + (n << 4);
        int cg = xc ^ ((dd >> 1) & 3);
        load_lds16(&xTb[(size_t)dd * S + j0 + cg * 8], &xb[((lw << 6) + (n << 4)) * 32]);
    }
}

// ---- fused attention: 8 waves = 2 j-groups x 4 row-waves, 32 rows/wave ----
// Block covers 128 i-rows; group g handles j-tiles {g, g+2, ...} (32 each).
// Each B-fragment (K or xT) read feeds 2 MFMA (row-halves hi=0,1): LDS read
// traffic per row is HALF the 16-row/wave structure. Cross-group lsum/oacc
// reduction via LDS at sweep boundaries. 256 blocks = 1/CU, 8 waves/CU.
__global__ __launch_bounds__(512, 2) void attn_fused(
    const bf16* __restrict__ Qbf, const bf16* __restrict__ Kbf,
    const bf16* __restrict__ xT, float* __restrict__ probs,
    bf16* __restrict__ attn) {
    int nblk = blockIdx.x;
    int lb = (nblk & 7) * 32 + (nblk >> 3);  // XCD-contiguous: 2 bh per XCD
    int bh = lb >> 4, b = bh >> 2, h = bh & 3;
    int strip = lb & 15;
    int t = threadIdx.x, w = t >> 6, l = t & 63;
    int lw = w & 3, g = w >> 2;
    int lr = l & 15, lq = l >> 4;
    const bf16* Q = Qbf + (size_t)bh * S * D;
    const bf16* K = Kbf + (size_t)bh * S * D;
    const bf16* xTb = xT + (size_t)b * D * S;
    int ibase = strip * 128 + lw * 32;

    __shared__ __align__(16) char smem[151552];
    bf16* kbg = (bf16*)smem + (size_t)g * 2 * 8192;           // [buf][32*256]
    bf16* xbg = (bf16*)(smem + 65536) + (size_t)g * 2 * 8192; // [buf][256*32]
    bf16* plw = (bf16*)(smem + 131072) + w * (32 * 40);       // per-wave P tile

    bf16x8 qf[2][8];
#pragma unroll
    for (int hi = 0; hi < 2; hi++)
#pragma unroll
        for (int kf = 0; kf < 8; kf++)
            qf[hi][kf] = *(const bf16x8*)
                &Q[(size_t)(ibase + hi * 16 + lr) * D + kf * 32 + lq * 8];

    // ---- sweep 1: lsum = sum_j exp2(s_ij) over this group's j-tiles ----
    float lsum[2][4] = {};
    stage_k_tile(K, kbg, g << 5, lw, l);
    for (int it = 0; it < 32; it++) {
        int cur = it & 1;
        if (it < 31) {
            stage_k_tile(K, kbg + (cur ^ 1) * 8192, (2 * (it + 1) + g) << 5, lw, l);
            asm volatile("s_waitcnt vmcnt(4)" ::: "memory");
        } else {
            asm volatile("s_waitcnt vmcnt(0)" ::: "memory");
        }
        __builtin_amdgcn_s_barrier();
        const bf16* kbc = kbg + cur * 8192;
#pragma unroll
        for (int subj = 0; subj < 2; subj++) {
            f32x4 a0 = {}, a1 = {};
#pragma unroll
            for (int kf = 0; kf < 8; kf++) {
                bf16x8 kfr = *(const bf16x8*)
                    &kbc[(subj * 16 + lr) * 256 + (((kf * 4 + lq) ^ (lr & 7)) * 8)];
                a0 = __builtin_amdgcn_mfma_f32_16x16x32_bf16(qf[0][kf], kfr, a0, 0, 0, 0);
                a1 = __builtin_amdgcn_mfma_f32_16x16x32_bf16(qf[1][kf], kfr, a1, 0, 0, 0);
            }
#pragma unroll
            for (int r = 0; r < 4; r++) {
                lsum[0][r] += exp2f(a0[r]);
                lsum[1][r] += exp2f(a1[r]);
            }
        }
        __builtin_amdgcn_s_barrier();
    }
#pragma unroll
    for (int hi = 0; hi < 2; hi++)
#pragma unroll
        for (int r = 0; r < 4; r++) {
            float s = lsum[hi][r];
            for (int off = 1; off < 16; off <<= 1) s += __shfl_xor(s, off);
            lsum[hi][r] = s;
        }
    // cross-group exchange of lsum (partner wave = w^4, same rows)
    {
        float* lex = (float*)smem;
        f32x4 v0 = {lsum[0][0], lsum[0][1], lsum[0][2], lsum[0][3]};
        f32x4 v1 = {lsum[1][0], lsum[1][1], lsum[1][2], lsum[1][3]};
        *(f32x4*)&lex[(w * 64 + l) * 8] = v0;
        *(f32x4*)&lex[(w * 64 + l) * 8 + 4] = v1;
        __syncthreads();
        f32x4 o0 = *(const f32x4*)&lex[((w ^ 4) * 64 + l) * 8];
        f32x4 o1 = *(const f32x4*)&lex[((w ^ 4) * 64 + l) * 8 + 4];
#pragma unroll
        for (int r = 0; r < 4; r++) {
            lsum[0][r] = 1.0f / (lsum[0][r] + o0[r]);
            lsum[1][r] = 1.0f / (lsum[1][r] + o1[r]);
        }
        __syncthreads();
    }

    // ---- sweep 2: recompute scores, write probs f32, fused PV ----
    f32x4 oacc0[16] = {};
    f32x4 oacc1[16] = {};
    float* probb = probs + (size_t)bh * S * S;
    stage_k_tile(K, kbg, g << 5, lw, l);
    stage_x_tile(xTb, xbg, g << 5, lw, l);
    for (int it = 0; it < 32; it++) {
        int cur = it & 1;
        int j0 = (2 * it + g) << 5;
        if (it < 31) {
            int jn = (2 * (it + 1) + g) << 5;
            stage_k_tile(K, kbg + (cur ^ 1) * 8192, jn, lw, l);
            stage_x_tile(xTb, xbg + (cur ^ 1) * 8192, jn, lw, l);
            asm volatile("s_waitcnt vmcnt(8)" ::: "memory");
        } else {
            asm volatile("s_waitcnt vmcnt(0)" ::: "memory");
        }
        __builtin_amdgcn_s_barrier();
        const bf16* kbc = kbg + cur * 8192;
        const bf16* xbc = xbg + cur * 8192;
#pragma unroll
        for (int subj = 0; subj < 2; subj++) {
            f32x4 a0 = {}, a1 = {};
#pragma unroll
            for (int kf = 0; kf < 8; kf++) {
                bf16x8 kfr = *(const bf16x8*)
                    &kbc[(subj * 16 + lr) * 256 + (((kf * 4 + lq) ^ (lr & 7)) * 8)];
                a0 = __builtin_amdgcn_mfma_f32_16x16x32_bf16(qf[0][kf], kfr, a0, 0, 0, 0);
                a1 = __builtin_amdgcn_mfma_f32_16x16x32_bf16(qf[1][kf], kfr, a1, 0, 0, 0);
            }
#pragma unroll
            for (int r = 0; r < 4; r++) {
                float p0 = exp2f(a0[r]) * lsum[0][r];
                float p1 = exp2f(a1[r]) * lsum[1][r];
                plw[(lq * 4 + r) * 40 + subj * 16 + lr] = (bf16)p0;
                plw[(16 + lq * 4 + r) * 40 + subj * 16 + lr] = (bf16)p1;
            }
        }
        // same-wave C->A layout round-trip (lgkmcnt only, no barrier)
        bf16x8 pf0 = *(const bf16x8*)&plw[lr * 40 + lq * 8];
        bf16x8 pf1 = *(const bf16x8*)&plw[(16 + lr) * 40 + lq * 8];
        {
            f32x4 s0, s1;
#pragma unroll
            for (int e = 0; e < 4; e++) { s0[e] = (float)pf0[e]; s1[e] = (float)pf0[e + 4]; }
            float* pp = &probb[(size_t)(ibase + lr) * S + j0 + lq * 8];
            *(f32x4*)pp = s0;
            *(f32x4*)(pp + 4) = s1;
#pragma unroll
            for (int e = 0; e < 4; e++) { s0[e] = (float)pf1[e]; s1[e] = (float)pf1[e + 4]; }
            float* pq = &probb[(size_t)(ibase + 16 + lr) * S + j0 + lq * 8];
            *(f32x4*)pq = s0;
            *(f32x4*)(pq + 4) = s1;
        }
#pragma unroll
        for (int dt = 0; dt < 16; dt++) {
            int dd = dt * 16 + lr;
            bf16x8 xf = *(const bf16x8*)&xbc[dd * 32 + ((lq ^ ((lr >> 1) & 3)) * 8)];
            oacc0[dt] = __builtin_amdgcn_mfma_f32_16x16x32_bf16(pf0, xf, oacc0[dt], 0, 0, 0);
            oacc1[dt] = __builtin_amdgcn_mfma_f32_16x16x32_bf16(pf1, xf, oacc1[dt], 0, 0, 0);
        }
        __builtin_amdgcn_s_barrier();
    }

    // ---- epilogue: cross-group oacc reduction, write attn ----
    float* osh = (float*)smem;  // [128][258] f32 (132 KB, buffers dead)
    if (g == 1) {
#pragma unroll
        for (int dt = 0; dt < 16; dt++)
#pragma unroll
            for (int rr = 0; rr < 4; rr++) {
                osh[(lw * 32 + lq * 4 + rr) * 258 + dt * 16 + lr] = oacc0[dt][rr];
                osh[(lw * 32 + 16 + lq * 4 + rr) * 258 + dt * 16 + lr] = oacc1[dt][rr];
            }
    }
    __syncthreads();
    if (g == 0) {
#pragma unroll
        for (int dt = 0; dt < 16; dt++)
#pragma unroll
            for (int rr = 0; rr < 4; rr++) {
                float v0 = oacc0[dt][rr] + osh[(lw * 32 + lq * 4 + rr) * 258 + dt * 16 + lr];
                float v1 = oacc1[dt][rr] + osh[(lw * 32 + 16 + lq * 4 + rr) * 258 + dt * 16 + lr];
                int r0 = ibase + lq * 4 + rr;
                int r1 = ibase + 16 + lq * 4 + rr;
                attn[((size_t)(b * S + r0)) * HD + h * D + dt * 16 + lr] = (bf16)v0;
                attn[((size_t)(b * S + r1)) * HD + h * D + dt * 16 + lr] = (bf16)v1;
            }
    }
}

// ------- final: out = attn @ Wv + x, then LayerNorm ------------------------
__global__ __launch_bounds__(256) void out_gemm_ln(
    const bf16* __restrict__ attn, const bf16* __restrict__ WvT,
    const float* __restrict__ x, const float* __restrict__ gamma,
    const float* __restrict__ beta, float* __restrict__ out) {
    int m0 = blockIdx.x * 16;
    int t = threadIdx.x, w = t >> 6, l = t & 63;
    int lr = l & 15, lq = l >> 4;
    int ncol0 = w * 64;
    f32x4 acc[4] = {};
    for (int k0 = 0; k0 < HD; k0 += 32) {
        bf16x8 af = *(const bf16x8*)&attn[(size_t)(m0 + lr) * HD + k0 + lq * 8];
#pragma unroll
        for (int dt = 0; dt < 4; dt++) {
            bf16x8 bfr =
                *(const bf16x8*)&WvT[(size_t)(ncol0 + dt * 16 + lr) * HD + k0 + lq * 8];
            acc[dt] = __builtin_amdgcn_mfma_f32_16x16x32_bf16(af, bfr, acc[dt], 0, 0, 0);
        }
    }
    float sum[4] = {0, 0, 0, 0}, sq[4] = {0, 0, 0, 0};
#pragma unroll
    for (int dt = 0; dt < 4; dt++)
#pragma unroll
        for (int rr = 0; rr < 4; rr++) {
            int row = m0 + lq * 4 + rr;
            float v = acc[dt][rr] + x[(size_t)row * D + ncol0 + dt * 16 + lr];
            acc[dt][rr] = v;
            sum[rr] += v;
            sq[rr] += v * v;
        }
#pragma unroll
    for (int rr = 0; rr < 4; rr++)
        for (int off = 1; off < 16; off <<= 1) {
            sum[rr] += __shfl_xor(sum[rr], off);
            sq[rr] += __shfl_xor(sq[rr], off);
        }
    __shared__ float part[4][16][2];
    if (lr == 0)
#pragma unroll
        for (int rr = 0; rr < 4; rr++) {
            part[w][lq * 4 + rr][0] = sum[rr];
            part[w][lq * 4 + rr][1] = sq[rr];
        }
    __syncthreads();
    float mu[4], rs[4];
#pragma unroll
    for (int rr = 0; rr < 4; rr++) {
        int rowi = lq * 4 + rr;
        float s = part[0][rowi][0] + part[1][rowi][0] + part[2][rowi][0] + part[3][rowi][0];
        float q = part[0][rowi][1] + part[1][rowi][1] + part[2][rowi][1] + part[3][rowi][1];
        mu[rr] = s * (1.0f / 256.0f);
        float var = q * (1.0f / 256.0f) - mu[rr] * mu[rr];
        rs[rr] = rsqrtf(var + 1e-5f);
    }
#pragma unroll
    for (int dt = 0; dt < 4; dt++) {
        int col = ncol0 + dt * 16 + lr;
        float g = gamma[col], be = beta[col];
#pragma unroll
        for (int rr = 0; rr < 4; rr++) {
            float v = (acc[dt][rr] - mu[rr]) * rs[rr] * g + be;
            out[(size_t)(m0 + lq * 4 + rr) * D + col] = v;
        }
    }
}

extern "C" void kernel_launch(void* const* d_in, const int* in_sizes, int n_in,
                              void* d_out, int out_size, void* d_ws, size_t ws_size,
                              hipStream_t stream) {
    const float* x = (const float*)d_in[0];
    const float* Wq = (const float*)d_in[1];
    const float* Wk = (const float*)d_in[2];
    const float* Wv = (const float*)d_in[3];
    const float* gamma = (const float*)d_in[4];
    const float* beta = (const float*)d_in[5];
    float* out = (float*)d_out;
    float* probs = out + (size_t)NROW * D;  // 2,097,152 floats of `out` first

    char* ws = (char*)d_ws;
    bf16* x_bf = (bf16*)ws;                      // 4 MB
    bf16* xT_bf = (bf16*)(ws + 4194304);         // 4 MB
    bf16* WqT = (bf16*)(ws + 8388608);           // 512 KB
    bf16* WkT = (bf16*)(ws + 8912896);           // 512 KB
    bf16* WvT = (bf16*)(ws + 9437184);           // 512 KB
    bf16* Qbf = (bf16*)(ws + 9961472);           // 16 MB
    bf16* Kbf = (bf16*)(ws + 26738688);          // 16 MB
    bf16* attn = (bf16*)(ws + 43515904);         // 16 MB

    prep_x<<<dim3(32, 4, 4), 256, 0, stream>>>(x, x_bf, xT_bf);
    prep_w<<<192, 256, 0, stream>>>(Wq, Wk, Wv, WqT, WkT, WvT);
    gemm_nt_bf16<<<dim3(16, 128, 2), 256, 0, stream>>>(x_bf, WqT, WkT, Qbf, Kbf,
                                                       HD, D);
    attn_fused<<<dim3(256), 512, 0, stream>>>(Qbf, Kbf, xT_bf, probs, attn);
    out_gemm_ln<<<512, 256, 0, stream>>>(attn, WvT, x, gamma, beta, out);
}